// Round 11
// baseline (674.174 us; speedup 1.0000x reference)
//
#include <hip/hip_runtime.h>
#include <hip/hip_fp16.h>

typedef unsigned char u8;
typedef unsigned short u16;

#define SCAN_B 256

// bucketed scatter params
#define NPB      128          // dst nodes per bucket
#define NPB_SH   7
#define P2_CAP   6144         // win entries per bucket
#define STG_CAP  6144         // fixed staging capacity per bucket (expected max ~5.4K)
#define P1_CHUNK 16384        // edges per part1 block
#define P1_T     256
#define P1_IT    (P1_CHUNK / P1_T)    // 64
#define NB_MAX   2048
#define GC_STR   16           // gcur stride (ints): one 64B line per bucket
#define STG_OFF  ((size_t)20 << 20)   // staging offset in d_out (u0 fp8 uses [0, 9.6MB))

// u stored as e4m3 bytes of (64 * u); scale keeps values in e4m3 NORMAL range
// (u ~ 0.002-0.05 -> 0.13-3.2), better rel precision than denormal-range storage.

// exact e4m3->f32 decode (incl denormals), 5 int ops; *2^120 folds into consumer FMA.
#define FP8_EXP_FIX 1.3292279957849159e36f    // 2^120
static __device__ __forceinline__ float fp8_raw(unsigned w) {
    // w: e4m3 byte in low 8 bits (upper bits ignored via masks)
    unsigned u = ((w << 24) & 0x80000000u) | ((w << 20) & 0x07F00000u);
    return __uint_as_float(u);
}
// f32 -> e4m3 with RNE; assumes |v| << 448, no NaN. ~7 ops.
static __device__ __forceinline__ unsigned f32_to_fp8w(float v) {
    unsigned u = __float_as_uint(v * 7.52316384526264e-37f);   // * 2^-120
    unsigned s = (u >> 24) & 0x80u;
    unsigned m = u & 0x7FFFFFFFu;
    unsigned r = (m + 0x7FFFFu + ((m >> 20) & 1u)) >> 20;      // RNE at bit 20
    if (r > 0x7Eu) r = 0x7Eu;                                   // clamp to max finite
    return s | r;
}

// ---------------- edge-format probe: int64-as-int32 (odd words zero) vs int32 ----------------
__global__ void detect_kernel(const int* __restrict__ edges, int* __restrict__ flag) {
    __shared__ int cnt[256];
    int t = threadIdx.x;
    int c = 0;
    for (int i = t; i < 32768; i += 256)
        if (edges[2 * i + 1] != 0) c++;
    cnt[t] = c;
    __syncthreads();
    for (int off = 128; off > 0; off >>= 1) {
        if (t < off) cnt[t] += cnt[t + off];
        __syncthreads();
    }
    if (t == 0) flag[0] = (cnt[0] < 8) ? 2 : 1;
}

// ---------------- fixed staging cursors: gcur[b*GC_STR] = b * STG_CAP ----------------
__global__ void gcur_fixed_init(int* __restrict__ gcur, int NB) {
    int b = blockIdx.x * blockDim.x + threadIdx.x;
    if (b < NB) gcur[b * GC_STR] = b * STG_CAP;
}

// ---------------- part1: partition edges into fixed-capacity dst-bucket regions --------
__global__ void part1_kernel(const int* __restrict__ edges, const int* __restrict__ flag,
                             int* __restrict__ gcur, unsigned* __restrict__ staging,
                             int E, int NB) {
    __shared__ int lcount[NB_MAX];
    __shared__ int lbase[NB_MAX];
    int t = threadIdx.x;
    int s = flag[0];
    long e0 = (long)blockIdx.x * P1_CHUNK;
    const int* dptr = edges + (long)E * s;   // dst stream base
    for (int b = t; b < NB; b += P1_T) lcount[b] = 0;
    __syncthreads();
    // count pass: 8 loads in flight per thread
    for (int j = 0; j < P1_IT; j += 8) {
        int dv[8]; bool vl[8];
        #pragma unroll
        for (int k = 0; k < 8; ++k) {
            long e = e0 + (long)(j + k) * P1_T + t;
            vl[k] = (e < E);
            dv[k] = vl[k] ? dptr[e * s] : 0;
        }
        #pragma unroll
        for (int k = 0; k < 8; ++k)
            if (vl[k]) atomicAdd(&lcount[dv[k] >> NPB_SH], 1);
    }
    __syncthreads();
    for (int b = t; b < NB; b += P1_T) {
        int c = lcount[b];
        lbase[b] = (c > 0) ? atomicAdd(&gcur[b * GC_STR], c) : 0;
        lcount[b] = 0;          // reuse as block-local cursor
    }
    __syncthreads();
    // scatter pass: 8 edges in flight per thread
    for (int j = 0; j < P1_IT; j += 8) {
        int dv[8], sv[8]; bool vl[8];
        #pragma unroll
        for (int k = 0; k < 8; ++k) {
            long e = e0 + (long)(j + k) * P1_T + t;
            vl[k] = (e < E);
            dv[k] = vl[k] ? dptr[e * s] : 0;
            sv[k] = vl[k] ? edges[e * s] : 0;
        }
        #pragma unroll
        for (int k = 0; k < 8; ++k) {
            if (vl[k]) {
                int b = dv[k] >> NPB_SH;
                int slot = atomicAdd(&lcount[b], 1);
                int pos = lbase[b] + slot;
                if (pos < (b + 1) * STG_CAP)        // overflow guard (never hit here)
                    staging[pos] = (unsigned)sv[k]
                                 | ((unsigned)(dv[k] & (NPB - 1)) << 20);
            }
        }
    }
}

// ---------------- bucket scan: bbase = excl-scan of (gcur[b*GC_STR] - b*STG_CAP) --------
__global__ void bucket_scan_kernel(const int* __restrict__ gcur, int* __restrict__ bbase,
                                   int NB) {
    __shared__ int sh[2][1024];
    int t = threadIdx.x;
    int i0 = 2 * t, i1 = 2 * t + 1;
    int a0 = (i0 < NB) ? (gcur[i0 * GC_STR] - i0 * STG_CAP) : 0;
    int a1 = (i1 < NB) ? (gcur[i1 * GC_STR] - i1 * STG_CAP) : 0;
    sh[0][t] = a0 + a1;
    __syncthreads();
    int src = 0;
    for (int off = 1; off < 1024; off <<= 1) {
        int x = sh[src][t] + ((t >= off) ? sh[src][t - off] : 0);
        sh[src ^ 1][t] = x;
        src ^= 1;
        __syncthreads();
    }
    int incl = sh[src][t];           // inclusive over pairs
    int excl = incl - (a0 + a1);
    if (i0 < NB) bbase[i0] = excl;
    if (i1 < NB) bbase[i1] = excl + a0;
    if (t == 1023) bbase[NB] = incl; // total == E
}

// ---------------- part2a: per-bucket node degrees -> row_ptr + dis/dis2/invd ------------
__global__ void __launch_bounds__(256) part2a_kernel(
        const int* __restrict__ gcur, const int* __restrict__ bbase,
        const unsigned* __restrict__ staging, int* __restrict__ row_ptr,
        float* __restrict__ dis, float* __restrict__ dis2, float* __restrict__ invd,
        int n, int E, int NB) {
    __shared__ int cnt[NPB];
    __shared__ int sc[2][NPB];
    int b = blockIdx.x;
    int t = threadIdx.x;
    int dlo = b << NPB_SH;
    int sbase = b * STG_CAP;
    int c = gcur[b * GC_STR] - sbase;    // edges in this bucket
    int base = bbase[b];                  // CSR base of bucket
    if (t < NPB) cnt[t] = 0;
    __syncthreads();
    for (int k = t; k < c; k += 256) {
        unsigned wd = staging[sbase + k];
        atomicAdd(&cnt[wd >> 20], 1);
    }
    __syncthreads();
    if (t < NPB) sc[0][t] = cnt[t];
    __syncthreads();
    int src = 0;
    for (int off = 1; off < NPB; off <<= 1) {
        if (t < NPB) {
            int x = sc[src][t] + ((t >= off) ? sc[src][t - off] : 0);
            sc[src ^ 1][t] = x;
        }
        src ^= 1;
        __syncthreads();
    }
    if (t < NPB) {
        int node = dlo + t;
        if (node < n) {
            int d = cnt[t];
            row_ptr[node] = base + sc[src][t] - d;   // exclusive
            float ds = (d > 0) ? rsqrtf((float)d) : 0.0f;
            dis[node]  = ds;
            dis2[node] = ds * ds;
            invd[node] = (d > 0) ? sqrtf((float)d) : 0.0f;
        }
    }
    if (b == 0 && t == 0) row_ptr[n] = E;
}

// ---------------- part2b: per-bucket exact CSR placement (src-only, 4B/edge) ------------
__global__ void __launch_bounds__(256) part2b_kernel(
        const int* __restrict__ row_ptr, const int* __restrict__ gcur,
        const unsigned* __restrict__ staging, int* __restrict__ cs, int n) {
    __shared__ int win[P2_CAP];
    __shared__ int cur[NPB];
    int b = blockIdx.x;
    int t = threadIdx.x;
    int dlo = b << NPB_SH;
    int sbase = b * STG_CAP;
    int cnt = gcur[b * GC_STR] - sbase;
    int base = row_ptr[dlo];
    if (t < NPB) {
        int node = dlo + t;
        cur[t] = (node < n) ? (row_ptr[node] - base) : 0;
    }
    __syncthreads();
    if (cnt <= P2_CAP) {
        for (int k = t; k < cnt; k += 256) {
            unsigned wd = staging[sbase + k];
            int p = atomicAdd(&cur[wd >> 20], 1);
            win[p] = (int)(wd & 0xFFFFF);
        }
        __syncthreads();
        for (int k = t; k < cnt; k += 256)
            cs[base + k] = win[k];
    } else {
        for (int k = t; k < cnt; k += 256) {
            unsigned wd = staging[sbase + k];
            int p = atomicAdd(&cur[wd >> 20], 1);
            cs[base + p] = (int)(wd & 0xFFFFF);
        }
    }
}

// ================= legacy fallback path (NB > NB_MAX / N too big / staging misfit) =======
__global__ void count_deg_kernel(const int* __restrict__ edges, const int* __restrict__ flag,
                                 int* __restrict__ deg, int E) {
    int e = blockIdx.x * blockDim.x + threadIdx.x;
    if (e >= E) return;
    int s = flag[0];
    int d = edges[(long)E * s + (long)e * s];
    atomicAdd(&deg[d], 1);
}

__global__ void scan_phase1(const int* __restrict__ deg, int* __restrict__ row_ptr,
                            int* __restrict__ bsum, int n) {
    __shared__ int sh[2][SCAN_B];
    int t = threadIdx.x;
    int gi = blockIdx.x * SCAN_B + t;
    int v = (gi < n) ? deg[gi] : 0;
    int src = 0;
    sh[0][t] = v;
    __syncthreads();
    for (int off = 1; off < SCAN_B; off <<= 1) {
        int x = sh[src][t] + ((t >= off) ? sh[src][t - off] : 0);
        sh[src ^ 1][t] = x;
        src ^= 1;
        __syncthreads();
    }
    int incl = sh[src][t];
    if (gi < n) row_ptr[gi] = incl - v;
    if (t == SCAN_B - 1) bsum[blockIdx.x] = incl;
}

__global__ void scan_phase2(int* __restrict__ bsum, int nb) {
    __shared__ int sh[1024];
    int t = threadIdx.x;
    sh[t] = (t < nb) ? bsum[t] : 0;
    __syncthreads();
    if (t == 0) {
        int acc = 0;
        for (int i = 0; i < nb; ++i) { int x = sh[i]; sh[i] = acc; acc += x; }
    }
    __syncthreads();
    if (t < nb) bsum[t] = sh[t];
}

__global__ void scan_phase3(const int* __restrict__ deg, const int* __restrict__ bsum,
                            int* __restrict__ row_ptr, int* __restrict__ cursor,
                            float* __restrict__ dis, float* __restrict__ dis2,
                            float* __restrict__ invd, int n, int E) {
    int gi = blockIdx.x * SCAN_B + threadIdx.x;
    if (gi < n) {
        int e = row_ptr[gi] + bsum[blockIdx.x];
        row_ptr[gi] = e;
        cursor[gi]  = e;
        int d = deg[gi];
        float ds = (d > 0) ? rsqrtf((float)d) : 0.0f;
        dis[gi]  = ds;
        dis2[gi] = ds * ds;
        invd[gi] = (d > 0) ? sqrtf((float)d) : 0.0f;
    }
    if (gi == 0) row_ptr[n] = E;
}

__global__ void scatter_kernel(const int* __restrict__ edges, const int* __restrict__ flag,
                               int* __restrict__ cursor, int* __restrict__ cs, int E) {
    int e = blockIdx.x * blockDim.x + threadIdx.x;
    if (e >= E) return;
    int s = flag[0];
    int sv = edges[(long)e * s];
    int dv = edges[(long)E * s + (long)e * s];
    int pos = atomicAdd(&cursor[dv], 1);
    cs[pos] = sv;
}
// ================= end legacy =================

// ================= fp8 u-storage (u = dis .* x, stored as e4m3 of 64u) =================
// u_{l+1}[d] = dis2[d] * sum_{s in N(d)} u_l[s];  sum_l x_l = invd .* sum_l u_l.
// Scale 64 is self-consistent through the recurrence (linear), applied at init, removed at final.
__global__ void init8_kernel(const float* __restrict__ eu, const float* __restrict__ ei,
                             const float* __restrict__ dis,
                             u8* __restrict__ u0, long NU64, long tot) {
    long i = (long)blockIdx.x * blockDim.x + threadIdx.x;
    if (i >= tot) return;
    float v = (i < NU64) ? eu[i] : ei[i - NU64];
    u0[i] = (u8)f32_to_fp8w(v * dis[i >> 6] * 64.0f);
}

// one wave per dst node; g=lane>>3 edge slot, h=lane&7 dim octet (8B of fp8).
// 4 chunks (32 edges) in flight per iteration for latency overlap.
#define ACC8(d)                                                         \
    a0 = fmaf(fp8_raw((d).x),       FP8_EXP_FIX, a0);                   \
    a1 = fmaf(fp8_raw((d).x >> 8),  FP8_EXP_FIX, a1);                   \
    a2 = fmaf(fp8_raw((d).x >> 16), FP8_EXP_FIX, a2);                   \
    a3 = fmaf(fp8_raw((d).x >> 24), FP8_EXP_FIX, a3);                   \
    a4 = fmaf(fp8_raw((d).y),       FP8_EXP_FIX, a4);                   \
    a5 = fmaf(fp8_raw((d).y >> 8),  FP8_EXP_FIX, a5);                   \
    a6 = fmaf(fp8_raw((d).y >> 16), FP8_EXP_FIX, a6);                   \
    a7 = fmaf(fp8_raw((d).y >> 24), FP8_EXP_FIX, a7);

__global__ void spmm8_kernel(const int* __restrict__ row_ptr, const int* __restrict__ cs,
                             const u8* __restrict__ uin, u8* __restrict__ uout,
                             const float* __restrict__ dis2, int n) {
    int wave = (blockIdx.x * blockDim.x + threadIdx.x) >> 6;
    int lane = threadIdx.x & 63;
    if (wave >= n) return;
    int beg = row_ptr[wave], end = row_ptr[wave + 1];
    int g = lane >> 3;
    int h = lane & 7;

    float a0 = 0.f, a1 = 0.f, a2 = 0.f, a3 = 0.f;
    float a4 = 0.f, a5 = 0.f, a6 = 0.f, a7 = 0.f;

    for (int i0 = beg + g; i0 < end; i0 += 32) {
        int i1 = i0 + 8, i2 = i0 + 16, i3 = i0 + 24;
        bool v1 = i1 < end, v2 = i2 < end, v3 = i3 < end;
        int s0 = cs[i0];
        int s1 = cs[v1 ? i1 : i0];
        int s2 = cs[v2 ? i2 : i0];
        int s3 = cs[v3 ? i3 : i0];
        uint2 d0 = *(const uint2*)(uin + ((long)s0 << 6) + (h << 3));
        uint2 d1 = *(const uint2*)(uin + ((long)s1 << 6) + (h << 3));
        uint2 d2 = *(const uint2*)(uin + ((long)s2 << 6) + (h << 3));
        uint2 d3 = *(const uint2*)(uin + ((long)s3 << 6) + (h << 3));
        if (!v1) { d1.x = 0; d1.y = 0; }
        if (!v2) { d2.x = 0; d2.y = 0; }
        if (!v3) { d3.x = 0; d3.y = 0; }
        ACC8(d0);
        ACC8(d1);
        ACC8(d2);
        ACC8(d3);
    }

    a0 += __shfl_xor(a0, 8);  a1 += __shfl_xor(a1, 8);
    a2 += __shfl_xor(a2, 8);  a3 += __shfl_xor(a3, 8);
    a4 += __shfl_xor(a4, 8);  a5 += __shfl_xor(a5, 8);
    a6 += __shfl_xor(a6, 8);  a7 += __shfl_xor(a7, 8);
    a0 += __shfl_xor(a0, 16); a1 += __shfl_xor(a1, 16);
    a2 += __shfl_xor(a2, 16); a3 += __shfl_xor(a3, 16);
    a4 += __shfl_xor(a4, 16); a5 += __shfl_xor(a5, 16);
    a6 += __shfl_xor(a6, 16); a7 += __shfl_xor(a7, 16);
    a0 += __shfl_xor(a0, 32); a1 += __shfl_xor(a1, 32);
    a2 += __shfl_xor(a2, 32); a3 += __shfl_xor(a3, 32);
    a4 += __shfl_xor(a4, 32); a5 += __shfl_xor(a5, 32);
    a6 += __shfl_xor(a6, 32); a7 += __shfl_xor(a7, 32);

    if (g == 0) {
        float s2 = dis2[wave];
        unsigned lo = f32_to_fp8w(a0 * s2)
                    | (f32_to_fp8w(a1 * s2) << 8)
                    | (f32_to_fp8w(a2 * s2) << 16)
                    | (f32_to_fp8w(a3 * s2) << 24);
        unsigned hi = f32_to_fp8w(a4 * s2)
                    | (f32_to_fp8w(a5 * s2) << 8)
                    | (f32_to_fp8w(a6 * s2) << 16)
                    | (f32_to_fp8w(a7 * s2) << 24);
        *(uint2*)(uout + ((long)wave << 6) + (h << 3)) = make_uint2(lo, hi);
    }
}

__global__ void final8_kernel(const u8* __restrict__ u1, const u8* __restrict__ u2,
                              const u8* __restrict__ u3, const u8* __restrict__ u4,
                              const float* __restrict__ eu, const float* __restrict__ ei,
                              const float* __restrict__ invd,
                              float* __restrict__ out, long NU64, long NI64) {
    long i = (long)blockIdx.x * blockDim.x + threadIdx.x;
    if (i >= NU64 + NI64) return;
    float base = (i < NU64) ? eu[i] : ei[i - NU64];
    float us = (fp8_raw(u1[i]) + fp8_raw(u2[i]) + fp8_raw(u3[i]) + fp8_raw(u4[i]))
               * FP8_EXP_FIX;
    float s = base + us * invd[i >> 6] * (1.0f / 64.0f);
    float v = s * (1.0f / 25.0f);
    if (i < NU64) {
        out[i] = v;
        out[NU64 + i] = base;
    } else {
        long j = i - NU64;
        out[2 * NU64 + j] = v;
        out[2 * NU64 + NI64 + j] = base;
    }
}
// ================= end fp8 path =================

extern "C" void kernel_launch(void* const* d_in, const int* in_sizes, int n_in,
                              void* d_out, int out_size, void* d_ws, size_t ws_size,
                              hipStream_t stream) {
    const float* eu = (const float*)d_in[0];
    const float* ei = (const float*)d_in[1];
    const int* edges = (const int*)d_in[2];
    float* out = (float*)d_out;

    const int NU = in_sizes[0] / 64;
    const int NI = in_sizes[1] / 64;
    const int N  = NU + NI;
    const int E  = in_sizes[2] / 2;
    const int NB = (N + NPB - 1) / NPB;     // 1172 for N=150K

    // workspace carve-up (256B aligned)
    char* w = (char*)d_ws;
    size_t off = 0;
    auto alloc = [&](size_t bytes) -> void* {
        void* p = w + off;
        off += (bytes + 255) & ~(size_t)255;
        return p;
    };
    int*   flag    = (int*)  alloc(256);
    int*   deg     = (int*)  alloc((size_t)N * 4);        // legacy path only
    int*   row_ptr = (int*)  alloc((size_t)(N + 1) * 4);
    int*   cursor  = (int*)  alloc((size_t)N * 4);        // legacy path only
    float* dis     = (float*)alloc((size_t)N * 4);
    float* dis2    = (float*)alloc((size_t)N * 4);
    float* invd    = (float*)alloc((size_t)N * 4);
    int*   bsum    = (int*)  alloc(1024 * 4);             // legacy path only
    int*   gcur    = (int*)  alloc((size_t)(NB + 1) * GC_STR * 4);  // line-padded
    int*   bbase   = (int*)  alloc((size_t)(NB + 1) * 4);
    int*   cs      = (int*)  alloc((size_t)E * 4);        // src-only CSR (4B/edge)
    const long NU64 = (long)NU * 64, NI64 = (long)NI * 64;
    const long tot = NU64 + NI64;          // = N*64
    u8* x1 = (u8*)alloc((size_t)tot);
    u8* x2 = (u8*)alloc((size_t)tot);
    u8* x3 = (u8*)alloc((size_t)tot);
    u8* x4 = (u8*)alloc((size_t)tot);

    // d_out scratch: u0 fp8 in [0, tot); u32 staging at STG_OFF (20MB).
    // out buffer is provably 2*tot floats = 8*tot bytes. out_size is in ELEMENTS (round-3
    // lesson) — never gate on it.
    const size_t out_bytes = (size_t)tot * 8;   // 76.8 MB
    u8*       x0      = (u8*)out;
    unsigned* staging = (unsigned*)((char*)out + STG_OFF);

    detect_kernel<<<1, 256, 0, stream>>>(edges, flag);

    bool fast = (NB <= NB_MAX) && (N < (1 << 20)) &&
                (STG_OFF + (size_t)NB * STG_CAP * 4 <= out_bytes) &&
                ((size_t)tot <= STG_OFF);

    if (fast) {
        gcur_fixed_init<<<(NB + 255) / 256, 256, 0, stream>>>(gcur, NB);
        part1_kernel<<<(E + P1_CHUNK - 1) / P1_CHUNK, P1_T, 0, stream>>>(edges, flag, gcur,
                                                                         staging, E, NB);
        bucket_scan_kernel<<<1, 1024, 0, stream>>>(gcur, bbase, NB);
        part2a_kernel<<<NB, 256, 0, stream>>>(gcur, bbase, staging, row_ptr,
                                              dis, dis2, invd, N, E, NB);
        part2b_kernel<<<NB, 256, 0, stream>>>(row_ptr, gcur, staging, cs, N);
    } else {
        const int nb = (N + SCAN_B - 1) / SCAN_B;
        hipMemsetAsync(deg, 0, (size_t)N * 4, stream);
        count_deg_kernel<<<(E + 255) / 256, 256, 0, stream>>>(edges, flag, deg, E);
        scan_phase1<<<nb, SCAN_B, 0, stream>>>(deg, row_ptr, bsum, N);
        scan_phase2<<<1, 1024, 0, stream>>>(bsum, nb);
        scan_phase3<<<nb, SCAN_B, 0, stream>>>(deg, bsum, row_ptr, cursor,
                                               dis, dis2, invd, N, E);
        scatter_kernel<<<(E + 255) / 256, 256, 0, stream>>>(edges, flag, cursor, cs, E);
    }

    const int nblk = (N + 3) / 4;
    const int eblk = (int)((tot + 255) / 256);
    init8_kernel<<<eblk, 256, 0, stream>>>(eu, ei, dis, x0, NU64, tot);
    spmm8_kernel<<<nblk, 256, 0, stream>>>(row_ptr, cs, x0, x1, dis2, N);
    spmm8_kernel<<<nblk, 256, 0, stream>>>(row_ptr, cs, x1, x2, dis2, N);
    spmm8_kernel<<<nblk, 256, 0, stream>>>(row_ptr, cs, x2, x3, dis2, N);
    spmm8_kernel<<<nblk, 256, 0, stream>>>(row_ptr, cs, x3, x4, dis2, N);
    final8_kernel<<<eblk, 256, 0, stream>>>(x1, x2, x3, x4, eu, ei, invd,
                                            out, NU64, NI64);
}

// Round 12
// 584.751 us; speedup vs baseline: 1.1529x; 1.1529x over previous
//
#include <hip/hip_runtime.h>
#include <hip/hip_fp16.h>

typedef unsigned char u8;
typedef unsigned short u16;
typedef float v2f __attribute__((ext_vector_type(2)));

#define SCAN_B 256

// bucketed scatter params
#define NPB      128          // dst nodes per bucket
#define NPB_SH   7
#define P2_CAP   6144         // win entries per bucket
#define STG_CAP  6144         // fixed staging capacity per bucket (expected max ~5.4K)
#define P1_CHUNK 16384        // edges per part1 block
#define P1_T     256
#define P1_IT    (P1_CHUNK / P1_T)    // 64
#define NB_MAX   2048
#define GC_STR   16           // gcur stride (ints): one 64B line per bucket
#define STG_OFF  ((size_t)20 << 20)   // staging offset in d_out (u0 fp8 uses [0, 9.6MB))

// u stored as e4m3 bytes of (64 * u); scale keeps values in e4m3 NORMAL range.

// exact e4m3->f32 decode fallback (5 int ops; *2^120 folds into consumer mul/add)
#define FP8_EXP_FIX 1.3292279957849159e36f    // 2^120
static __device__ __forceinline__ float fp8_raw(unsigned w) {
    unsigned u = ((w << 24) & 0x80000000u) | ((w << 20) & 0x07F00000u);
    return __uint_as_float(u);
}
// f32 -> e4m3 with RNE; assumes |v| << 448, no NaN. ~7 ops. (epilogue-only)
static __device__ __forceinline__ unsigned f32_to_fp8w(float v) {
    unsigned u = __float_as_uint(v * 7.52316384526264e-37f);   // * 2^-120
    unsigned s = (u >> 24) & 0x80u;
    unsigned m = u & 0x7FFFFFFFu;
    unsigned r = (m + 0x7FFFFu + ((m >> 20) & 1u)) >> 20;      // RNE at bit 20
    if (r > 0x7Eu) r = 0x7Eu;
    return s | r;
}

// packed e4m3 pair -> 2x f32. HW v_cvt_pk_f32_fp8 when available (round 7: it is),
// bit-trick fallback otherwise.
template <bool HI>
static __device__ __forceinline__ v2f pk2(unsigned w) {
#if __has_builtin(__builtin_amdgcn_cvt_pk_f32_fp8)
    return __builtin_amdgcn_cvt_pk_f32_fp8((int)w, HI);
#else
    v2f r;
    r.x = fp8_raw(HI ? (w >> 16) : w) * FP8_EXP_FIX;
    r.y = fp8_raw(HI ? (w >> 24) : (w >> 8)) * FP8_EXP_FIX;
    return r;
#endif
}

// ---------------- edge-format probe: int64-as-int32 (odd words zero) vs int32 ----------------
__global__ void detect_kernel(const int* __restrict__ edges, int* __restrict__ flag) {
    __shared__ int cnt[256];
    int t = threadIdx.x;
    int c = 0;
    for (int i = t; i < 32768; i += 256)
        if (edges[2 * i + 1] != 0) c++;
    cnt[t] = c;
    __syncthreads();
    for (int off = 128; off > 0; off >>= 1) {
        if (t < off) cnt[t] += cnt[t + off];
        __syncthreads();
    }
    if (t == 0) flag[0] = (cnt[0] < 8) ? 2 : 1;
}

// ---------------- fixed staging cursors: gcur[b*GC_STR] = b * STG_CAP ----------------
__global__ void gcur_fixed_init(int* __restrict__ gcur, int NB) {
    int b = blockIdx.x * blockDim.x + threadIdx.x;
    if (b < NB) gcur[b * GC_STR] = b * STG_CAP;
}

// ---------------- part1: partition edges into fixed-capacity dst-bucket regions --------
__global__ void part1_kernel(const int* __restrict__ edges, const int* __restrict__ flag,
                             int* __restrict__ gcur, unsigned* __restrict__ staging,
                             int E, int NB) {
    __shared__ int lcount[NB_MAX];
    __shared__ int lbase[NB_MAX];
    int t = threadIdx.x;
    int s = flag[0];
    long e0 = (long)blockIdx.x * P1_CHUNK;
    const int* dptr = edges + (long)E * s;   // dst stream base
    for (int b = t; b < NB; b += P1_T) lcount[b] = 0;
    __syncthreads();
    // count pass: 8 loads in flight per thread
    for (int j = 0; j < P1_IT; j += 8) {
        int dv[8]; bool vl[8];
        #pragma unroll
        for (int k = 0; k < 8; ++k) {
            long e = e0 + (long)(j + k) * P1_T + t;
            vl[k] = (e < E);
            dv[k] = vl[k] ? dptr[e * s] : 0;
        }
        #pragma unroll
        for (int k = 0; k < 8; ++k)
            if (vl[k]) atomicAdd(&lcount[dv[k] >> NPB_SH], 1);
    }
    __syncthreads();
    for (int b = t; b < NB; b += P1_T) {
        int c = lcount[b];
        lbase[b] = (c > 0) ? atomicAdd(&gcur[b * GC_STR], c) : 0;
        lcount[b] = 0;          // reuse as block-local cursor
    }
    __syncthreads();
    // scatter pass: 8 edges in flight per thread
    for (int j = 0; j < P1_IT; j += 8) {
        int dv[8], sv[8]; bool vl[8];
        #pragma unroll
        for (int k = 0; k < 8; ++k) {
            long e = e0 + (long)(j + k) * P1_T + t;
            vl[k] = (e < E);
            dv[k] = vl[k] ? dptr[e * s] : 0;
            sv[k] = vl[k] ? edges[e * s] : 0;
        }
        #pragma unroll
        for (int k = 0; k < 8; ++k) {
            if (vl[k]) {
                int b = dv[k] >> NPB_SH;
                int slot = atomicAdd(&lcount[b], 1);
                int pos = lbase[b] + slot;
                if (pos < (b + 1) * STG_CAP)        // overflow guard (never hit here)
                    staging[pos] = (unsigned)sv[k]
                                 | ((unsigned)(dv[k] & (NPB - 1)) << 20);
            }
        }
    }
}

// ---------------- bucket scan: bbase = excl-scan of (gcur[b*GC_STR] - b*STG_CAP) --------
__global__ void bucket_scan_kernel(const int* __restrict__ gcur, int* __restrict__ bbase,
                                   int NB) {
    __shared__ int sh[2][1024];
    int t = threadIdx.x;
    int i0 = 2 * t, i1 = 2 * t + 1;
    int a0 = (i0 < NB) ? (gcur[i0 * GC_STR] - i0 * STG_CAP) : 0;
    int a1 = (i1 < NB) ? (gcur[i1 * GC_STR] - i1 * STG_CAP) : 0;
    sh[0][t] = a0 + a1;
    __syncthreads();
    int src = 0;
    for (int off = 1; off < 1024; off <<= 1) {
        int x = sh[src][t] + ((t >= off) ? sh[src][t - off] : 0);
        sh[src ^ 1][t] = x;
        src ^= 1;
        __syncthreads();
    }
    int incl = sh[src][t];           // inclusive over pairs
    int excl = incl - (a0 + a1);
    if (i0 < NB) bbase[i0] = excl;
    if (i1 < NB) bbase[i1] = excl + a0;
    if (t == 1023) bbase[NB] = incl; // total == E
}

// ---------------- part2a: per-bucket node degrees -> row_ptr + dis/dis2/invd ------------
__global__ void __launch_bounds__(256) part2a_kernel(
        const int* __restrict__ gcur, const int* __restrict__ bbase,
        const unsigned* __restrict__ staging, int* __restrict__ row_ptr,
        float* __restrict__ dis, float* __restrict__ dis2, float* __restrict__ invd,
        int n, int E, int NB) {
    __shared__ int cnt[NPB];
    __shared__ int sc[2][NPB];
    int b = blockIdx.x;
    int t = threadIdx.x;
    int dlo = b << NPB_SH;
    int sbase = b * STG_CAP;
    int c = gcur[b * GC_STR] - sbase;    // edges in this bucket
    int base = bbase[b];                  // CSR base of bucket
    if (t < NPB) cnt[t] = 0;
    __syncthreads();
    for (int k = t; k < c; k += 256) {
        unsigned wd = staging[sbase + k];
        atomicAdd(&cnt[wd >> 20], 1);
    }
    __syncthreads();
    if (t < NPB) sc[0][t] = cnt[t];
    __syncthreads();
    int src = 0;
    for (int off = 1; off < NPB; off <<= 1) {
        if (t < NPB) {
            int x = sc[src][t] + ((t >= off) ? sc[src][t - off] : 0);
            sc[src ^ 1][t] = x;
        }
        src ^= 1;
        __syncthreads();
    }
    if (t < NPB) {
        int node = dlo + t;
        if (node < n) {
            int d = cnt[t];
            row_ptr[node] = base + sc[src][t] - d;   // exclusive
            float ds = (d > 0) ? rsqrtf((float)d) : 0.0f;
            dis[node]  = ds;
            dis2[node] = ds * ds;
            invd[node] = (d > 0) ? sqrtf((float)d) : 0.0f;
        }
    }
    if (b == 0 && t == 0) row_ptr[n] = E;
}

// ---------------- part2b: per-bucket exact CSR placement (src-only, 4B/edge) ------------
__global__ void __launch_bounds__(256) part2b_kernel(
        const int* __restrict__ row_ptr, const int* __restrict__ gcur,
        const unsigned* __restrict__ staging, int* __restrict__ cs, int n) {
    __shared__ int win[P2_CAP];
    __shared__ int cur[NPB];
    int b = blockIdx.x;
    int t = threadIdx.x;
    int dlo = b << NPB_SH;
    int sbase = b * STG_CAP;
    int cnt = gcur[b * GC_STR] - sbase;
    int base = row_ptr[dlo];
    if (t < NPB) {
        int node = dlo + t;
        cur[t] = (node < n) ? (row_ptr[node] - base) : 0;
    }
    __syncthreads();
    if (cnt <= P2_CAP) {
        for (int k = t; k < cnt; k += 256) {
            unsigned wd = staging[sbase + k];
            int p = atomicAdd(&cur[wd >> 20], 1);
            win[p] = (int)(wd & 0xFFFFF);
        }
        __syncthreads();
        for (int k = t; k < cnt; k += 256)
            cs[base + k] = win[k];
    } else {
        for (int k = t; k < cnt; k += 256) {
            unsigned wd = staging[sbase + k];
            int p = atomicAdd(&cur[wd >> 20], 1);
            cs[base + p] = (int)(wd & 0xFFFFF);
        }
    }
}

// ================= legacy fallback path (NB > NB_MAX / N too big / staging misfit) =======
__global__ void count_deg_kernel(const int* __restrict__ edges, const int* __restrict__ flag,
                                 int* __restrict__ deg, int E) {
    int e = blockIdx.x * blockDim.x + threadIdx.x;
    if (e >= E) return;
    int s = flag[0];
    int d = edges[(long)E * s + (long)e * s];
    atomicAdd(&deg[d], 1);
}

__global__ void scan_phase1(const int* __restrict__ deg, int* __restrict__ row_ptr,
                            int* __restrict__ bsum, int n) {
    __shared__ int sh[2][SCAN_B];
    int t = threadIdx.x;
    int gi = blockIdx.x * SCAN_B + t;
    int v = (gi < n) ? deg[gi] : 0;
    int src = 0;
    sh[0][t] = v;
    __syncthreads();
    for (int off = 1; off < SCAN_B; off <<= 1) {
        int x = sh[src][t] + ((t >= off) ? sh[src][t - off] : 0);
        sh[src ^ 1][t] = x;
        src ^= 1;
        __syncthreads();
    }
    int incl = sh[src][t];
    if (gi < n) row_ptr[gi] = incl - v;
    if (t == SCAN_B - 1) bsum[blockIdx.x] = incl;
}

__global__ void scan_phase2(int* __restrict__ bsum, int nb) {
    __shared__ int sh[1024];
    int t = threadIdx.x;
    sh[t] = (t < nb) ? bsum[t] : 0;
    __syncthreads();
    if (t == 0) {
        int acc = 0;
        for (int i = 0; i < nb; ++i) { int x = sh[i]; sh[i] = acc; acc += x; }
    }
    __syncthreads();
    if (t < nb) bsum[t] = sh[t];
}

__global__ void scan_phase3(const int* __restrict__ deg, const int* __restrict__ bsum,
                            int* __restrict__ row_ptr, int* __restrict__ cursor,
                            float* __restrict__ dis, float* __restrict__ dis2,
                            float* __restrict__ invd, int n, int E) {
    int gi = blockIdx.x * SCAN_B + threadIdx.x;
    if (gi < n) {
        int e = row_ptr[gi] + bsum[blockIdx.x];
        row_ptr[gi] = e;
        cursor[gi]  = e;
        int d = deg[gi];
        float ds = (d > 0) ? rsqrtf((float)d) : 0.0f;
        dis[gi]  = ds;
        dis2[gi] = ds * ds;
        invd[gi] = (d > 0) ? sqrtf((float)d) : 0.0f;
    }
    if (gi == 0) row_ptr[n] = E;
}

__global__ void scatter_kernel(const int* __restrict__ edges, const int* __restrict__ flag,
                               int* __restrict__ cursor, int* __restrict__ cs, int E) {
    int e = blockIdx.x * blockDim.x + threadIdx.x;
    if (e >= E) return;
    int s = flag[0];
    int sv = edges[(long)e * s];
    int dv = edges[(long)E * s + (long)e * s];
    int pos = atomicAdd(&cursor[dv], 1);
    cs[pos] = sv;
}
// ================= end legacy =================

// ================= fp8 u-storage (u = dis .* x, stored as e4m3 of 64u) =================
// u_{l+1}[d] = dis2[d] * sum_{s in N(d)} u_l[s];  sum_l x_l = invd .* sum_l u_l.
__global__ void init8_kernel(const float* __restrict__ eu, const float* __restrict__ ei,
                             const float* __restrict__ dis,
                             u8* __restrict__ u0, long NU64, long tot) {
    long i = (long)blockIdx.x * blockDim.x + threadIdx.x;
    if (i >= tot) return;
    float v = (i < NU64) ? eu[i] : ei[i - NU64];
    u0[i] = (u8)f32_to_fp8w(v * dis[i >> 6] * 64.0f);
}

// one wave per dst node; g=lane>>3 edge slot, h=lane&7 dim octet (8B of fp8).
// 16 edges (2 chunks of 8) in flight; HW cvt_pk_f32_fp8 decode (round 7 proven).
__global__ void spmm8_kernel(const int* __restrict__ row_ptr, const int* __restrict__ cs,
                             const u8* __restrict__ uin, u8* __restrict__ uout,
                             const float* __restrict__ dis2, int n) {
    int wave = (blockIdx.x * blockDim.x + threadIdx.x) >> 6;
    int lane = threadIdx.x & 63;
    if (wave >= n) return;
    int beg = row_ptr[wave], end = row_ptr[wave + 1];
    int g = lane >> 3;
    int h = lane & 7;

    float a0 = 0.f, a1 = 0.f, a2 = 0.f, a3 = 0.f;
    float a4 = 0.f, a5 = 0.f, a6 = 0.f, a7 = 0.f;

    for (int iA = beg + g; iA < end; iA += 16) {
        int iB = iA + 8;
        bool vB = iB < end;
        int sa = cs[iA];
        int sb = cs[vB ? iB : iA];
        uint2 dA = *(const uint2*)(uin + ((long)sa << 6) + (h << 3));
        uint2 dB = *(const uint2*)(uin + ((long)sb << 6) + (h << 3));
        if (!vB) { dB.x = 0; dB.y = 0; }

        v2f p;
        p = pk2<false>(dA.x); a0 += p.x; a1 += p.y;
        p = pk2<true>(dA.x);  a2 += p.x; a3 += p.y;
        p = pk2<false>(dA.y); a4 += p.x; a5 += p.y;
        p = pk2<true>(dA.y);  a6 += p.x; a7 += p.y;
        p = pk2<false>(dB.x); a0 += p.x; a1 += p.y;
        p = pk2<true>(dB.x);  a2 += p.x; a3 += p.y;
        p = pk2<false>(dB.y); a4 += p.x; a5 += p.y;
        p = pk2<true>(dB.y);  a6 += p.x; a7 += p.y;
    }

    a0 += __shfl_xor(a0, 8);  a1 += __shfl_xor(a1, 8);
    a2 += __shfl_xor(a2, 8);  a3 += __shfl_xor(a3, 8);
    a4 += __shfl_xor(a4, 8);  a5 += __shfl_xor(a5, 8);
    a6 += __shfl_xor(a6, 8);  a7 += __shfl_xor(a7, 8);
    a0 += __shfl_xor(a0, 16); a1 += __shfl_xor(a1, 16);
    a2 += __shfl_xor(a2, 16); a3 += __shfl_xor(a3, 16);
    a4 += __shfl_xor(a4, 16); a5 += __shfl_xor(a5, 16);
    a6 += __shfl_xor(a6, 16); a7 += __shfl_xor(a7, 16);
    a0 += __shfl_xor(a0, 32); a1 += __shfl_xor(a1, 32);
    a2 += __shfl_xor(a2, 32); a3 += __shfl_xor(a3, 32);
    a4 += __shfl_xor(a4, 32); a5 += __shfl_xor(a5, 32);
    a6 += __shfl_xor(a6, 32); a7 += __shfl_xor(a7, 32);

    if (g == 0) {
        float s2 = dis2[wave];
        unsigned lo = f32_to_fp8w(a0 * s2)
                    | (f32_to_fp8w(a1 * s2) << 8)
                    | (f32_to_fp8w(a2 * s2) << 16)
                    | (f32_to_fp8w(a3 * s2) << 24);
        unsigned hi = f32_to_fp8w(a4 * s2)
                    | (f32_to_fp8w(a5 * s2) << 8)
                    | (f32_to_fp8w(a6 * s2) << 16)
                    | (f32_to_fp8w(a7 * s2) << 24);
        *(uint2*)(uout + ((long)wave << 6) + (h << 3)) = make_uint2(lo, hi);
    }
}

__global__ void final8_kernel(const u8* __restrict__ u1, const u8* __restrict__ u2,
                              const u8* __restrict__ u3, const u8* __restrict__ u4,
                              const float* __restrict__ eu, const float* __restrict__ ei,
                              const float* __restrict__ invd,
                              float* __restrict__ out, long NU64, long NI64) {
    long i = (long)blockIdx.x * blockDim.x + threadIdx.x;
    if (i >= NU64 + NI64) return;
    float base = (i < NU64) ? eu[i] : ei[i - NU64];
    float us = (fp8_raw(u1[i]) + fp8_raw(u2[i]) + fp8_raw(u3[i]) + fp8_raw(u4[i]))
               * FP8_EXP_FIX;
    float s = base + us * invd[i >> 6] * (1.0f / 64.0f);
    float v = s * (1.0f / 25.0f);
    if (i < NU64) {
        out[i] = v;
        out[NU64 + i] = base;
    } else {
        long j = i - NU64;
        out[2 * NU64 + j] = v;
        out[2 * NU64 + NI64 + j] = base;
    }
}
// ================= end fp8 path =================

extern "C" void kernel_launch(void* const* d_in, const int* in_sizes, int n_in,
                              void* d_out, int out_size, void* d_ws, size_t ws_size,
                              hipStream_t stream) {
    const float* eu = (const float*)d_in[0];
    const float* ei = (const float*)d_in[1];
    const int* edges = (const int*)d_in[2];
    float* out = (float*)d_out;

    const int NU = in_sizes[0] / 64;
    const int NI = in_sizes[1] / 64;
    const int N  = NU + NI;
    const int E  = in_sizes[2] / 2;
    const int NB = (N + NPB - 1) / NPB;     // 1172 for N=150K

    // workspace carve-up (256B aligned)
    char* w = (char*)d_ws;
    size_t off = 0;
    auto alloc = [&](size_t bytes) -> void* {
        void* p = w + off;
        off += (bytes + 255) & ~(size_t)255;
        return p;
    };
    int*   flag    = (int*)  alloc(256);
    int*   deg     = (int*)  alloc((size_t)N * 4);        // legacy path only
    int*   row_ptr = (int*)  alloc((size_t)(N + 1) * 4);
    int*   cursor  = (int*)  alloc((size_t)N * 4);        // legacy path only
    float* dis     = (float*)alloc((size_t)N * 4);
    float* dis2    = (float*)alloc((size_t)N * 4);
    float* invd    = (float*)alloc((size_t)N * 4);
    int*   bsum    = (int*)  alloc(1024 * 4);             // legacy path only
    int*   gcur    = (int*)  alloc((size_t)(NB + 1) * GC_STR * 4);  // line-padded
    int*   bbase   = (int*)  alloc((size_t)(NB + 1) * 4);
    int*   cs      = (int*)  alloc((size_t)E * 4);        // src-only CSR (4B/edge)
    const long NU64 = (long)NU * 64, NI64 = (long)NI * 64;
    const long tot = NU64 + NI64;          // = N*64
    u8* x1 = (u8*)alloc((size_t)tot);
    u8* x2 = (u8*)alloc((size_t)tot);
    u8* x3 = (u8*)alloc((size_t)tot);
    u8* x4 = (u8*)alloc((size_t)tot);

    // d_out scratch: u0 fp8 in [0, tot); u32 staging at STG_OFF (20MB).
    // out buffer is provably 2*tot floats = 8*tot bytes. out_size is in ELEMENTS (round-3
    // lesson) — never gate on it.
    const size_t out_bytes = (size_t)tot * 8;   // 76.8 MB
    u8*       x0      = (u8*)out;
    unsigned* staging = (unsigned*)((char*)out + STG_OFF);

    detect_kernel<<<1, 256, 0, stream>>>(edges, flag);

    bool fast = (NB <= NB_MAX) && (N < (1 << 20)) &&
                (STG_OFF + (size_t)NB * STG_CAP * 4 <= out_bytes) &&
                ((size_t)tot <= STG_OFF);

    if (fast) {
        gcur_fixed_init<<<(NB + 255) / 256, 256, 0, stream>>>(gcur, NB);
        part1_kernel<<<(E + P1_CHUNK - 1) / P1_CHUNK, P1_T, 0, stream>>>(edges, flag, gcur,
                                                                         staging, E, NB);
        bucket_scan_kernel<<<1, 1024, 0, stream>>>(gcur, bbase, NB);
        part2a_kernel<<<NB, 256, 0, stream>>>(gcur, bbase, staging, row_ptr,
                                              dis, dis2, invd, N, E, NB);
        part2b_kernel<<<NB, 256, 0, stream>>>(row_ptr, gcur, staging, cs, N);
    } else {
        const int nb = (N + SCAN_B - 1) / SCAN_B;
        hipMemsetAsync(deg, 0, (size_t)N * 4, stream);
        count_deg_kernel<<<(E + 255) / 256, 256, 0, stream>>>(edges, flag, deg, E);
        scan_phase1<<<nb, SCAN_B, 0, stream>>>(deg, row_ptr, bsum, N);
        scan_phase2<<<1, 1024, 0, stream>>>(bsum, nb);
        scan_phase3<<<nb, SCAN_B, 0, stream>>>(deg, bsum, row_ptr, cursor,
                                               dis, dis2, invd, N, E);
        scatter_kernel<<<(E + 255) / 256, 256, 0, stream>>>(edges, flag, cursor, cs, E);
    }

    const int nblk = (N + 3) / 4;
    const int eblk = (int)((tot + 255) / 256);
    init8_kernel<<<eblk, 256, 0, stream>>>(eu, ei, dis, x0, NU64, tot);
    spmm8_kernel<<<nblk, 256, 0, stream>>>(row_ptr, cs, x0, x1, dis2, N);
    spmm8_kernel<<<nblk, 256, 0, stream>>>(row_ptr, cs, x1, x2, dis2, N);
    spmm8_kernel<<<nblk, 256, 0, stream>>>(row_ptr, cs, x2, x3, dis2, N);
    spmm8_kernel<<<nblk, 256, 0, stream>>>(row_ptr, cs, x3, x4, dis2, N);
    final8_kernel<<<eblk, 256, 0, stream>>>(x1, x2, x3, x4, eu, ei, invd,
                                            out, NU64, NI64);
}

// Round 13
// 467.022 us; speedup vs baseline: 1.4436x; 1.2521x over previous
//
#include <hip/hip_runtime.h>
#include <hip/hip_fp16.h>

typedef unsigned char u8;
typedef unsigned short u16;
typedef float v2f __attribute__((ext_vector_type(2)));

#define SCAN_B 256

// bucketed scatter params
#define NPB      128          // dst nodes per bucket
#define NPB_SH   7
#define P2_CAP   6144         // win entries per bucket
#define STG_CAP  6144         // fixed staging capacity per bucket (expected max ~5.4K)
#define P1_CHUNK 16384        // edges per part1 block
#define P1_T     256
#define P1_IT    (P1_CHUNK / P1_T)    // 64
#define NB_MAX   2048
#define GC_STR   16           // gcur stride (ints): one 64B line per bucket
#define STG_OFF  ((size_t)20 << 20)   // staging offset in d_out (u0 fp8 uses [0, 9.6MB))

// u stored as e4m3 bytes of (64 * u); scale keeps values in e4m3 NORMAL range.

// exact e4m3->f32 decode fallback (5 int ops; *2^120 folds into consumer mul/add)
#define FP8_EXP_FIX 1.3292279957849159e36f    // 2^120
static __device__ __forceinline__ float fp8_raw(unsigned w) {
    unsigned u = ((w << 24) & 0x80000000u) | ((w << 20) & 0x07F00000u);
    return __uint_as_float(u);
}
// f32 -> e4m3 with RNE; assumes |v| << 448, no NaN. ~7 ops. (epilogue-only)
static __device__ __forceinline__ unsigned f32_to_fp8w(float v) {
    unsigned u = __float_as_uint(v * 7.52316384526264e-37f);   // * 2^-120
    unsigned s = (u >> 24) & 0x80u;
    unsigned m = u & 0x7FFFFFFFu;
    unsigned r = (m + 0x7FFFFu + ((m >> 20) & 1u)) >> 20;      // RNE at bit 20
    if (r > 0x7Eu) r = 0x7Eu;
    return s | r;
}

// packed e4m3 pair -> 2x f32. HW v_cvt_pk_f32_fp8 when available (round 7/12 proven),
// bit-trick fallback otherwise.
template <bool HI>
static __device__ __forceinline__ v2f pk2(unsigned w) {
#if __has_builtin(__builtin_amdgcn_cvt_pk_f32_fp8)
    return __builtin_amdgcn_cvt_pk_f32_fp8((int)w, HI);
#else
    v2f r;
    r.x = fp8_raw(HI ? (w >> 16) : w) * FP8_EXP_FIX;
    r.y = fp8_raw(HI ? (w >> 24) : (w >> 8)) * FP8_EXP_FIX;
    return r;
#endif
}

// ---------------- edge-format probe: int64-as-int32 (odd words zero) vs int32 ----------------
__global__ void detect_kernel(const int* __restrict__ edges, int* __restrict__ flag) {
    __shared__ int cnt[256];
    int t = threadIdx.x;
    int c = 0;
    for (int i = t; i < 32768; i += 256)
        if (edges[2 * i + 1] != 0) c++;
    cnt[t] = c;
    __syncthreads();
    for (int off = 128; off > 0; off >>= 1) {
        if (t < off) cnt[t] += cnt[t + off];
        __syncthreads();
    }
    if (t == 0) flag[0] = (cnt[0] < 8) ? 2 : 1;
}

// ---------------- fixed staging cursors: gcur[b*GC_STR] = b * STG_CAP ----------------
__global__ void gcur_fixed_init(int* __restrict__ gcur, int NB) {
    int b = blockIdx.x * blockDim.x + threadIdx.x;
    if (b < NB) gcur[b * GC_STR] = b * STG_CAP;
}

// ---------------- part1: partition edges into fixed-capacity dst-bucket regions --------
__global__ void part1_kernel(const int* __restrict__ edges, const int* __restrict__ flag,
                             int* __restrict__ gcur, unsigned* __restrict__ staging,
                             int E, int NB) {
    __shared__ int lcount[NB_MAX];
    __shared__ int lbase[NB_MAX];
    int t = threadIdx.x;
    int s = flag[0];
    long e0 = (long)blockIdx.x * P1_CHUNK;
    const int* dptr = edges + (long)E * s;   // dst stream base
    for (int b = t; b < NB; b += P1_T) lcount[b] = 0;
    __syncthreads();
    // count pass: 8 loads in flight per thread
    for (int j = 0; j < P1_IT; j += 8) {
        int dv[8]; bool vl[8];
        #pragma unroll
        for (int k = 0; k < 8; ++k) {
            long e = e0 + (long)(j + k) * P1_T + t;
            vl[k] = (e < E);
            dv[k] = vl[k] ? dptr[e * s] : 0;
        }
        #pragma unroll
        for (int k = 0; k < 8; ++k)
            if (vl[k]) atomicAdd(&lcount[dv[k] >> NPB_SH], 1);
    }
    __syncthreads();
    for (int b = t; b < NB; b += P1_T) {
        int c = lcount[b];
        lbase[b] = (c > 0) ? atomicAdd(&gcur[b * GC_STR], c) : 0;
        lcount[b] = 0;          // reuse as block-local cursor
    }
    __syncthreads();
    // scatter pass: 8 edges in flight per thread
    for (int j = 0; j < P1_IT; j += 8) {
        int dv[8], sv[8]; bool vl[8];
        #pragma unroll
        for (int k = 0; k < 8; ++k) {
            long e = e0 + (long)(j + k) * P1_T + t;
            vl[k] = (e < E);
            dv[k] = vl[k] ? dptr[e * s] : 0;
            sv[k] = vl[k] ? edges[e * s] : 0;
        }
        #pragma unroll
        for (int k = 0; k < 8; ++k) {
            if (vl[k]) {
                int b = dv[k] >> NPB_SH;
                int slot = atomicAdd(&lcount[b], 1);
                int pos = lbase[b] + slot;
                if (pos < (b + 1) * STG_CAP)        // overflow guard (never hit here)
                    staging[pos] = (unsigned)sv[k]
                                 | ((unsigned)(dv[k] & (NPB - 1)) << 20);
            }
        }
    }
}

// ---------------- bucket scan: bbase = excl-scan of (gcur[b*GC_STR] - b*STG_CAP) --------
__global__ void bucket_scan_kernel(const int* __restrict__ gcur, int* __restrict__ bbase,
                                   int NB) {
    __shared__ int sh[2][1024];
    int t = threadIdx.x;
    int i0 = 2 * t, i1 = 2 * t + 1;
    int a0 = (i0 < NB) ? (gcur[i0 * GC_STR] - i0 * STG_CAP) : 0;
    int a1 = (i1 < NB) ? (gcur[i1 * GC_STR] - i1 * STG_CAP) : 0;
    sh[0][t] = a0 + a1;
    __syncthreads();
    int src = 0;
    for (int off = 1; off < 1024; off <<= 1) {
        int x = sh[src][t] + ((t >= off) ? sh[src][t - off] : 0);
        sh[src ^ 1][t] = x;
        src ^= 1;
        __syncthreads();
    }
    int incl = sh[src][t];           // inclusive over pairs
    int excl = incl - (a0 + a1);
    if (i0 < NB) bbase[i0] = excl;
    if (i1 < NB) bbase[i1] = excl + a0;
    if (t == 1023) bbase[NB] = incl; // total == E
}

// ---------------- part2a: per-bucket node degrees -> row_ptr + dis/dis2/invd ------------
__global__ void __launch_bounds__(256) part2a_kernel(
        const int* __restrict__ gcur, const int* __restrict__ bbase,
        const unsigned* __restrict__ staging, int* __restrict__ row_ptr,
        float* __restrict__ dis, float* __restrict__ dis2, float* __restrict__ invd,
        int n, int E, int NB) {
    __shared__ int cnt[NPB];
    __shared__ int sc[2][NPB];
    int b = blockIdx.x;
    int t = threadIdx.x;
    int dlo = b << NPB_SH;
    int sbase = b * STG_CAP;
    int c = gcur[b * GC_STR] - sbase;    // edges in this bucket
    int base = bbase[b];                  // CSR base of bucket
    if (t < NPB) cnt[t] = 0;
    __syncthreads();
    for (int k = t; k < c; k += 256) {
        unsigned wd = staging[sbase + k];
        atomicAdd(&cnt[wd >> 20], 1);
    }
    __syncthreads();
    if (t < NPB) sc[0][t] = cnt[t];
    __syncthreads();
    int src = 0;
    for (int off = 1; off < NPB; off <<= 1) {
        if (t < NPB) {
            int x = sc[src][t] + ((t >= off) ? sc[src][t - off] : 0);
            sc[src ^ 1][t] = x;
        }
        src ^= 1;
        __syncthreads();
    }
    if (t < NPB) {
        int node = dlo + t;
        if (node < n) {
            int d = cnt[t];
            row_ptr[node] = base + sc[src][t] - d;   // exclusive
            float ds = (d > 0) ? rsqrtf((float)d) : 0.0f;
            dis[node]  = ds;
            dis2[node] = ds * ds;
            invd[node] = (d > 0) ? sqrtf((float)d) : 0.0f;
        }
    }
    if (b == 0 && t == 0) row_ptr[n] = E;
}

// ---------------- part2b: per-bucket exact CSR placement (src-only, 4B/edge) ------------
__global__ void __launch_bounds__(256) part2b_kernel(
        const int* __restrict__ row_ptr, const int* __restrict__ gcur,
        const unsigned* __restrict__ staging, int* __restrict__ cs, int n) {
    __shared__ int win[P2_CAP];
    __shared__ int cur[NPB];
    int b = blockIdx.x;
    int t = threadIdx.x;
    int dlo = b << NPB_SH;
    int sbase = b * STG_CAP;
    int cnt = gcur[b * GC_STR] - sbase;
    int base = row_ptr[dlo];
    if (t < NPB) {
        int node = dlo + t;
        cur[t] = (node < n) ? (row_ptr[node] - base) : 0;
    }
    __syncthreads();
    if (cnt <= P2_CAP) {
        for (int k = t; k < cnt; k += 256) {
            unsigned wd = staging[sbase + k];
            int p = atomicAdd(&cur[wd >> 20], 1);
            win[p] = (int)(wd & 0xFFFFF);
        }
        __syncthreads();
        for (int k = t; k < cnt; k += 256)
            cs[base + k] = win[k];
    } else {
        for (int k = t; k < cnt; k += 256) {
            unsigned wd = staging[sbase + k];
            int p = atomicAdd(&cur[wd >> 20], 1);
            cs[base + p] = (int)(wd & 0xFFFFF);
        }
    }
}

// ================= legacy fallback path (NB > NB_MAX / N too big / staging misfit) =======
__global__ void count_deg_kernel(const int* __restrict__ edges, const int* __restrict__ flag,
                                 int* __restrict__ deg, int E) {
    int e = blockIdx.x * blockDim.x + threadIdx.x;
    if (e >= E) return;
    int s = flag[0];
    int d = edges[(long)E * s + (long)e * s];
    atomicAdd(&deg[d], 1);
}

__global__ void scan_phase1(const int* __restrict__ deg, int* __restrict__ row_ptr,
                            int* __restrict__ bsum, int n) {
    __shared__ int sh[2][SCAN_B];
    int t = threadIdx.x;
    int gi = blockIdx.x * SCAN_B + t;
    int v = (gi < n) ? deg[gi] : 0;
    int src = 0;
    sh[0][t] = v;
    __syncthreads();
    for (int off = 1; off < SCAN_B; off <<= 1) {
        int x = sh[src][t] + ((t >= off) ? sh[src][t - off] : 0);
        sh[src ^ 1][t] = x;
        src ^= 1;
        __syncthreads();
    }
    int incl = sh[src][t];
    if (gi < n) row_ptr[gi] = incl - v;
    if (t == SCAN_B - 1) bsum[blockIdx.x] = incl;
}

__global__ void scan_phase2(int* __restrict__ bsum, int nb) {
    __shared__ int sh[1024];
    int t = threadIdx.x;
    sh[t] = (t < nb) ? bsum[t] : 0;
    __syncthreads();
    if (t == 0) {
        int acc = 0;
        for (int i = 0; i < nb; ++i) { int x = sh[i]; sh[i] = acc; acc += x; }
    }
    __syncthreads();
    if (t < nb) bsum[t] = sh[t];
}

__global__ void scan_phase3(const int* __restrict__ deg, const int* __restrict__ bsum,
                            int* __restrict__ row_ptr, int* __restrict__ cursor,
                            float* __restrict__ dis, float* __restrict__ dis2,
                            float* __restrict__ invd, int n, int E) {
    int gi = blockIdx.x * SCAN_B + threadIdx.x;
    if (gi < n) {
        int e = row_ptr[gi] + bsum[blockIdx.x];
        row_ptr[gi] = e;
        cursor[gi]  = e;
        int d = deg[gi];
        float ds = (d > 0) ? rsqrtf((float)d) : 0.0f;
        dis[gi]  = ds;
        dis2[gi] = ds * ds;
        invd[gi] = (d > 0) ? sqrtf((float)d) : 0.0f;
    }
    if (gi == 0) row_ptr[n] = E;
}

__global__ void scatter_kernel(const int* __restrict__ edges, const int* __restrict__ flag,
                               int* __restrict__ cursor, int* __restrict__ cs, int E) {
    int e = blockIdx.x * blockDim.x + threadIdx.x;
    if (e >= E) return;
    int s = flag[0];
    int sv = edges[(long)e * s];
    int dv = edges[(long)E * s + (long)e * s];
    int pos = atomicAdd(&cursor[dv], 1);
    cs[pos] = sv;
}
// ================= end legacy =================

// ================= fp8 u-storage (u = dis .* x, stored as e4m3 of 64u) =================
// u_{l+1}[d] = dis2[d] * sum_{s in N(d)} u_l[s];  sum_l x_l = invd .* sum_l u_l.
__global__ void init8_kernel(const float* __restrict__ eu, const float* __restrict__ ei,
                             const float* __restrict__ dis,
                             u8* __restrict__ u0, long NU64, long tot) {
    long i = (long)blockIdx.x * blockDim.x + threadIdx.x;
    if (i >= tot) return;
    float v = (i < NU64) ? eu[i] : ei[i - NU64];
    u0[i] = (u8)f32_to_fp8w(v * dis[i >> 6] * 64.0f);
}

// TWO rows per wave: half = lane>>5 selects the row, within a half g=(lane>>3)&3 is the
// edge slot (4 slots, 2 chunks in flight = 8 edges/row), h=lane&7 the dim octet.
// Halved wave count amortizes the per-row epilogue; reduction needs only xor 8,16
// (both stay inside a 32-lane half). v2f accumulators -> v_pk_add_f32 packed adds.
__global__ void spmm8_kernel(const int* __restrict__ row_ptr, const int* __restrict__ cs,
                             const u8* __restrict__ uin, u8* __restrict__ uout,
                             const float* __restrict__ dis2, int n) {
    int wid  = (blockIdx.x * blockDim.x + threadIdx.x) >> 6;
    int lane = threadIdx.x & 63;
    int half = lane >> 5;
    int node = 2 * wid + half;
    int g = (lane >> 3) & 3;     // edge slot 0..3 within half
    int h = lane & 7;            // dim octet

    bool act = node < n;
    int beg = 0, end = 0;
    if (act) { beg = row_ptr[node]; end = row_ptr[node + 1]; }

    v2f a01 = {0.f, 0.f}, a23 = {0.f, 0.f}, a45 = {0.f, 0.f}, a67 = {0.f, 0.f};

    for (int iA = beg + g; iA < end; iA += 8) {
        int iB = iA + 4;
        bool vB = iB < end;
        int sa = cs[iA];
        int sb = cs[vB ? iB : iA];
        uint2 dA = *(const uint2*)(uin + ((long)sa << 6) + (h << 3));
        uint2 dB = *(const uint2*)(uin + ((long)sb << 6) + (h << 3));
        if (!vB) { dB.x = 0; dB.y = 0; }

        a01 += pk2<false>(dA.x); a23 += pk2<true>(dA.x);
        a45 += pk2<false>(dA.y); a67 += pk2<true>(dA.y);
        a01 += pk2<false>(dB.x); a23 += pk2<true>(dB.x);
        a45 += pk2<false>(dB.y); a67 += pk2<true>(dB.y);
    }

    // reduce across the 4 edge slots: xor 8, xor 16 (stay within the 32-lane half)
    a01.x += __shfl_xor(a01.x, 8);  a01.y += __shfl_xor(a01.y, 8);
    a23.x += __shfl_xor(a23.x, 8);  a23.y += __shfl_xor(a23.y, 8);
    a45.x += __shfl_xor(a45.x, 8);  a45.y += __shfl_xor(a45.y, 8);
    a67.x += __shfl_xor(a67.x, 8);  a67.y += __shfl_xor(a67.y, 8);
    a01.x += __shfl_xor(a01.x, 16); a01.y += __shfl_xor(a01.y, 16);
    a23.x += __shfl_xor(a23.x, 16); a23.y += __shfl_xor(a23.y, 16);
    a45.x += __shfl_xor(a45.x, 16); a45.y += __shfl_xor(a45.y, 16);
    a67.x += __shfl_xor(a67.x, 16); a67.y += __shfl_xor(a67.y, 16);

    if (act && g == 0) {
        float s2 = dis2[node];
        unsigned lo = f32_to_fp8w(a01.x * s2)
                    | (f32_to_fp8w(a01.y * s2) << 8)
                    | (f32_to_fp8w(a23.x * s2) << 16)
                    | (f32_to_fp8w(a23.y * s2) << 24);
        unsigned hi = f32_to_fp8w(a45.x * s2)
                    | (f32_to_fp8w(a45.y * s2) << 8)
                    | (f32_to_fp8w(a67.x * s2) << 16)
                    | (f32_to_fp8w(a67.y * s2) << 24);
        *(uint2*)(uout + ((long)node << 6) + (h << 3)) = make_uint2(lo, hi);
    }
}

__global__ void final8_kernel(const u8* __restrict__ u1, const u8* __restrict__ u2,
                              const u8* __restrict__ u3, const u8* __restrict__ u4,
                              const float* __restrict__ eu, const float* __restrict__ ei,
                              const float* __restrict__ invd,
                              float* __restrict__ out, long NU64, long NI64) {
    long i = (long)blockIdx.x * blockDim.x + threadIdx.x;
    if (i >= NU64 + NI64) return;
    float base = (i < NU64) ? eu[i] : ei[i - NU64];
    float us = (fp8_raw(u1[i]) + fp8_raw(u2[i]) + fp8_raw(u3[i]) + fp8_raw(u4[i]))
               * FP8_EXP_FIX;
    float s = base + us * invd[i >> 6] * (1.0f / 64.0f);
    float v = s * (1.0f / 25.0f);
    if (i < NU64) {
        out[i] = v;
        out[NU64 + i] = base;
    } else {
        long j = i - NU64;
        out[2 * NU64 + j] = v;
        out[2 * NU64 + NI64 + j] = base;
    }
}
// ================= end fp8 path =================

extern "C" void kernel_launch(void* const* d_in, const int* in_sizes, int n_in,
                              void* d_out, int out_size, void* d_ws, size_t ws_size,
                              hipStream_t stream) {
    const float* eu = (const float*)d_in[0];
    const float* ei = (const float*)d_in[1];
    const int* edges = (const int*)d_in[2];
    float* out = (float*)d_out;

    const int NU = in_sizes[0] / 64;
    const int NI = in_sizes[1] / 64;
    const int N  = NU + NI;
    const int E  = in_sizes[2] / 2;
    const int NB = (N + NPB - 1) / NPB;     // 1172 for N=150K

    // workspace carve-up (256B aligned)
    char* w = (char*)d_ws;
    size_t off = 0;
    auto alloc = [&](size_t bytes) -> void* {
        void* p = w + off;
        off += (bytes + 255) & ~(size_t)255;
        return p;
    };
    int*   flag    = (int*)  alloc(256);
    int*   deg     = (int*)  alloc((size_t)N * 4);        // legacy path only
    int*   row_ptr = (int*)  alloc((size_t)(N + 1) * 4);
    int*   cursor  = (int*)  alloc((size_t)N * 4);        // legacy path only
    float* dis     = (float*)alloc((size_t)N * 4);
    float* dis2    = (float*)alloc((size_t)N * 4);
    float* invd    = (float*)alloc((size_t)N * 4);
    int*   bsum    = (int*)  alloc(1024 * 4);             // legacy path only
    int*   gcur    = (int*)  alloc((size_t)(NB + 1) * GC_STR * 4);  // line-padded
    int*   bbase   = (int*)  alloc((size_t)(NB + 1) * 4);
    int*   cs      = (int*)  alloc((size_t)E * 4);        // src-only CSR (4B/edge)
    const long NU64 = (long)NU * 64, NI64 = (long)NI * 64;
    const long tot = NU64 + NI64;          // = N*64
    u8* x1 = (u8*)alloc((size_t)tot);
    u8* x2 = (u8*)alloc((size_t)tot);
    u8* x3 = (u8*)alloc((size_t)tot);
    u8* x4 = (u8*)alloc((size_t)tot);

    // d_out scratch: u0 fp8 in [0, tot); u32 staging at STG_OFF (20MB).
    // out buffer is provably 2*tot floats = 8*tot bytes. out_size is in ELEMENTS (round-3
    // lesson) — never gate on it.
    const size_t out_bytes = (size_t)tot * 8;   // 76.8 MB
    u8*       x0      = (u8*)out;
    unsigned* staging = (unsigned*)((char*)out + STG_OFF);

    detect_kernel<<<1, 256, 0, stream>>>(edges, flag);

    bool fast = (NB <= NB_MAX) && (N < (1 << 20)) &&
                (STG_OFF + (size_t)NB * STG_CAP * 4 <= out_bytes) &&
                ((size_t)tot <= STG_OFF);

    if (fast) {
        gcur_fixed_init<<<(NB + 255) / 256, 256, 0, stream>>>(gcur, NB);
        part1_kernel<<<(E + P1_CHUNK - 1) / P1_CHUNK, P1_T, 0, stream>>>(edges, flag, gcur,
                                                                         staging, E, NB);
        bucket_scan_kernel<<<1, 1024, 0, stream>>>(gcur, bbase, NB);
        part2a_kernel<<<NB, 256, 0, stream>>>(gcur, bbase, staging, row_ptr,
                                              dis, dis2, invd, N, E, NB);
        part2b_kernel<<<NB, 256, 0, stream>>>(row_ptr, gcur, staging, cs, N);
    } else {
        const int nb = (N + SCAN_B - 1) / SCAN_B;
        hipMemsetAsync(deg, 0, (size_t)N * 4, stream);
        count_deg_kernel<<<(E + 255) / 256, 256, 0, stream>>>(edges, flag, deg, E);
        scan_phase1<<<nb, SCAN_B, 0, stream>>>(deg, row_ptr, bsum, N);
        scan_phase2<<<1, 1024, 0, stream>>>(bsum, nb);
        scan_phase3<<<nb, SCAN_B, 0, stream>>>(deg, bsum, row_ptr, cursor,
                                               dis, dis2, invd, N, E);
        scatter_kernel<<<(E + 255) / 256, 256, 0, stream>>>(edges, flag, cursor, cs, E);
    }

    const int nblk = (N + 7) / 8;   // 2 rows per wave, 4 waves per 256-thread block
    const int eblk = (int)((tot + 255) / 256);
    init8_kernel<<<eblk, 256, 0, stream>>>(eu, ei, dis, x0, NU64, tot);
    spmm8_kernel<<<nblk, 256, 0, stream>>>(row_ptr, cs, x0, x1, dis2, N);
    spmm8_kernel<<<nblk, 256, 0, stream>>>(row_ptr, cs, x1, x2, dis2, N);
    spmm8_kernel<<<nblk, 256, 0, stream>>>(row_ptr, cs, x2, x3, dis2, N);
    spmm8_kernel<<<nblk, 256, 0, stream>>>(row_ptr, cs, x3, x4, dis2, N);
    final8_kernel<<<eblk, 256, 0, stream>>>(x1, x2, x3, x4, eu, ei, invd,
                                            out, NU64, NI64);
}